// Round 1
// baseline (69.141 us; speedup 1.0000x reference)
//
#include <hip/hip_runtime.h>
#include <math.h>

// Problem constants (from reference)
#define K     9
#define NB    64
#define NH    32
#define NW    32
#define NCELLS (NH * NW)          // 1024
#define NT    50
#define NUM_LABELS (2 * K + 3)    // 21
#define CH    (2 * K + 2)         // 20 channels per batch (NA=1, NC=1)
#define THF   80.0f
#define SHARPF 2.0f
#define SILF  0.6f
#define NOOBJF 1.0f
#define OBJF  5.0f
#define IMWF  640.0f
#define IMHF  480.0f

__global__ __launch_bounds__(256) void region_loss_kernel(
    const float* __restrict__ outp,   // (NB, 20, NH, NW)
    const float* __restrict__ tgt,    // (NB, 50*21)
    const int*   __restrict__ epoch_p,
    float*       __restrict__ loss_out)
{
    __shared__ float sX[NT][K];   // gt corner x in pixels (x*640)
    __shared__ float sY[NT][K];   // gt corner y in pixels (y*480)
    __shared__ float sTx[NT][K];  // tx = x*NW - gi0
    __shared__ float sTy[NT][K];  // ty = y*NH - gj0
    __shared__ int   sGi[NT], sGj[NT], sFlag[NT];
    __shared__ int   sNv;
    __shared__ float sRed[4];

    const int b    = blockIdx.x >> 2;          // 4 blocks per batch
    const int tid  = threadIdx.x;
    const int cell = ((blockIdx.x & 3) << 8) + tid;
    const int gi   = cell & (NW - 1);
    const int gj   = cell >> 5;

    // ---- stage targets for this batch ----
    if (tid < NT) {
        const float* tp = tgt + (size_t)b * NT * NUM_LABELS + tid * NUM_LABELS + 1;
        float x0 = tp[0];
        sFlag[tid] = (x0 != 0.0f) ? 1 : 0;
        int gi0 = (int)floorf(tp[0] * (float)NW);
        int gj0 = (int)floorf(tp[1] * (float)NH);
        sGi[tid] = gi0;
        sGj[tid] = gj0;
        #pragma unroll
        for (int k = 0; k < K; k++) {
            float xk = tp[2 * k];
            float yk = tp[2 * k + 1];
            sX[tid][k]  = xk * IMWF;
            sY[tid][k]  = yk * IMHF;
            sTx[tid][k] = xk * (float)NW - (float)gi0;
            sTy[tid][k] = yk * (float)NH - (float)gj0;
        }
    }
    __syncthreads();
    if (tid == 0) {
        int nv = 0;
        while (nv < NT && sFlag[nv]) nv++;   // cumprod-valid prefix
        sNv = nv;
    }
    __syncthreads();
    const int nv = sNv;

    // ---- load this cell's prediction channels (coalesced) ----
    const float* ob = outp + ((size_t)b * CH) * NCELLS + cell;
    float xs[K], ys[K];
    #pragma unroll
    for (int k = 0; k < K; k++) {
        xs[k] = ob[(2 * k) * NCELLS];
        ys[k] = ob[(2 * k + 1) * NCELLS];
    }
    float conf_logit = ob[(2 * K) * NCELLS];

    // sigmoid on corner 0 and on conf only
    xs[0] = 1.0f / (1.0f + __expf(-xs[0]));
    ys[0] = 1.0f / (1.0f + __expf(-ys[0]));
    const float conf = 1.0f / (1.0f + __expf(-conf_logit));

    // predicted corners in pixel space: px*IMW = (x+gi)*(640/32), py*IMH = (y+gj)*(480/32)
    float PX[K], PY[K];
    #pragma unroll
    for (int k = 0; k < K; k++) {
        PX[k] = (xs[k] + (float)gi) * (IMWF / (float)NW);   // *20
        PY[k] = (ys[k] + (float)gj) * (IMHF / (float)NH);   // *15
    }

    const float inv_den = 1.0f / (__expf(SHARPF) - 1.0f + 1e-5f);
    float cur    = 0.0f;
    float tconf  = 0.0f;
    int   tmatch = -1;

    for (int t = 0; t < nv; t++) {
        float s = 0.0f;
        #pragma unroll
        for (int k = 0; k < K; k++) {
            float dx = sX[t][k] - PX[k];
            float dy = sY[t][k] - PY[k];
            float d2 = dx * dx + dy * dy;
            if (d2 < THF * THF) {               // dist < TH (sqrt is monotone)
                float dist = sqrtf(d2);
                s += (__expf(SHARPF * (1.0f - dist * (1.0f / THF))) - 1.0f) * inv_den;
            }
        }
        float ct = s * (1.0f / (float)K);       // mean over corners
        cur = fmaxf(cur, ct);
        if (gi == sGi[t] && gj == sGj[t]) {     // this cell holds target t (last wins)
            tconf  = ct;                        // == conf_gt for this target
            tmatch = t;
        }
    }

    float mask = (tmatch >= 0) ? OBJF : ((cur > SILF) ? 0.0f : NOOBJF);

    const int epoch = *epoch_p;
    float d = conf - tconf;
    float local = (epoch > 15) ? (0.5f * d * d * mask) : 0.0f;

    if (tmatch >= 0) {
        float sxy = 0.0f;
        #pragma unroll
        for (int k = 0; k < K; k++) {
            float ex = xs[k] - sTx[tmatch][k];
            float ey = ys[k] - sTy[tmatch][k];
            sxy += ex * ex + ey * ey;
        }
        local += 0.5f * sxy;
    }

    // ---- block reduction: wave shuffle, then LDS across 4 waves ----
    #pragma unroll
    for (int off = 32; off > 0; off >>= 1)
        local += __shfl_down(local, off, 64);
    const int wave = tid >> 6;
    const int lane = tid & 63;
    if (lane == 0) sRed[wave] = local;
    __syncthreads();
    if (tid == 0) {
        float s = sRed[0] + sRed[1] + sRed[2] + sRed[3];
        atomicAdd(loss_out, s);
    }
}

extern "C" void kernel_launch(void* const* d_in, const int* in_sizes, int n_in,
                              void* d_out, int out_size, void* d_ws, size_t ws_size,
                              hipStream_t stream) {
    const float* outp  = (const float*)d_in[0];
    const float* tgt   = (const float*)d_in[1];
    const int*   epoch = (const int*)d_in[2];
    float* loss = (float*)d_out;

    hipMemsetAsync(loss, 0, sizeof(float) * (size_t)out_size, stream);
    region_loss_kernel<<<dim3(NB * 4), dim3(256), 0, stream>>>(outp, tgt, epoch, loss);
}